// Round 1
// baseline (14543.028 us; speedup 1.0000x reference)
//
#include <hip/hip_runtime.h>
#include <math.h>

// ---------------- problem constants ----------------
#define CB 8
#define CT 16
#define CN 256
#define CD 1280
#define CH 512
#define CS 3
#define CM (CB*CT*CN)      // 32768 rows
#define CBS (CB*CS)        // 24
#define CH3 (3*CH)         // 1536
#define CH2 (2*CH)         // 1024
#define NITER 3

// ---------------- workspace layout (float offsets) ----------------
#define OFS_P1   0ULL                       // P1, later feats (in-place): CM*CH
#define OFS_M1   16777216ULL                // M1, later k_buf (overwrite): CM*CH
#define OFS_V    33554432ULL                // v_buf: CM*CH
#define OFS_ST   50331648ULL                // rowstats: CM*2
#define OFS_WQT  50397184ULL                // 512*512
#define OFS_WHHT (OFS_WQT + 262144ULL)      // 512*1536
#define OFS_WIHT (OFS_WHHT + 786432ULL)     // 512*1536
#define OFS_WM1T (OFS_WIHT + 786432ULL)     // 512*1024
#define OFS_WM2T (OFS_WM1T + 524288ULL)     // 1024*512
#define OFS_WTOT (OFS_WM2T + 524288ULL)     // 512*512
#define OFS_WTQT (OFS_WTOT + 262144ULL)
#define OFS_WTKT (OFS_WTQT + 262144ULL)
#define OFS_WTVT (OFS_WTKT + 262144ULL)
#define OFS_SLOTS (OFS_WTVT + 262144ULL)    // 24*512
#define OFS_Q    (OFS_SLOTS + 12288ULL)
#define OFS_GH   (OFS_Q + 12288ULL)         // 24*1536
#define OFS_ATTN (OFS_GH + 36864ULL)        // 24*256
#define OFS_U    (OFS_ATTN + 6144ULL)       // 24*512
#define OFS_Z    (OFS_U + 12288ULL)         // 32
#define OFS_H    (OFS_Z + 32ULL)            // 24*512
#define OFS_Y    (OFS_H + 12288ULL)         // 24*1024
#define OFS_TQKV (OFS_Y + 24576ULL)         // 384*1536
#define OFS_TO   (OFS_TQKV + 589824ULL)     // 384*512
#define OFS_BAR  (OFS_TO + 196608ULL)       // barrier counters (uints)

// ---------------- GEMM tiling ----------------
#define BM 128
#define BN 128
#define BK 8

// ================= init: slots0, zero agg + barrier =================
__global__ __launch_bounds__(256) void k_init(const float* __restrict__ noise,
                                              const float* __restrict__ mu,
                                              const float* __restrict__ sigma,
                                              float* __restrict__ ws,
                                              float* __restrict__ out) {
  int i = blockIdx.x * 256 + threadIdx.x;
  if (i < 12288) {
    int sj = i % 1536;  // (s,h) index into mu/sigma [1,3,512]
    ws[OFS_SLOTS + i] = mu[sj] + sigma[sj] * noise[i];
    out[i] = 0.0f;      // zero slots_agg accumulation region
  }
  if (i < 16) {
    unsigned* bar = (unsigned*)(ws + OFS_BAR);
    bar[i] = 0u;
  }
}

// ================= weight transposes for coalesced GEMV phases =================
__global__ __launch_bounds__(256) void k_transpose(const float* __restrict__ w_q,
                                                   const float* __restrict__ w_hh,
                                                   const float* __restrict__ w_ih,
                                                   const float* __restrict__ w_mlp1,
                                                   const float* __restrict__ w_mlp2,
                                                   const float* __restrict__ w_to,
                                                   const float* __restrict__ w_tq,
                                                   const float* __restrict__ w_tk,
                                                   const float* __restrict__ w_tv,
                                                   float* __restrict__ ws) {
  const float* src; float* dst; int R, C;
  switch (blockIdx.z) {
    case 0: src = w_q;    dst = ws + OFS_WQT;  R = 512;  C = 512;  break;
    case 1: src = w_hh;   dst = ws + OFS_WHHT; R = 1536; C = 512;  break;
    case 2: src = w_ih;   dst = ws + OFS_WIHT; R = 1536; C = 512;  break;
    case 3: src = w_mlp1; dst = ws + OFS_WM1T; R = 1024; C = 512;  break;
    case 4: src = w_mlp2; dst = ws + OFS_WM2T; R = 512;  C = 1024; break;
    case 5: src = w_to;   dst = ws + OFS_WTOT; R = 512;  C = 512;  break;
    case 6: src = w_tq;   dst = ws + OFS_WTQT; R = 512;  C = 512;  break;
    case 7: src = w_tk;   dst = ws + OFS_WTKT; R = 512;  C = 512;  break;
    default: src = w_tv;  dst = ws + OFS_WTVT; R = 512;  C = 512;  break;
  }
  int r0 = blockIdx.y * 32, c0 = blockIdx.x * 32;
  if (r0 >= R || c0 >= C) return;
  __shared__ float tile[32][33];
  int tx = threadIdx.x & 31, ty = threadIdx.x >> 5;  // 32 x 8
  for (int i = ty; i < 32; i += 8)
    tile[i][tx] = src[(size_t)(r0 + i) * C + c0 + tx];
  __syncthreads();
  for (int i = ty; i < 32; i += 8)
    dst[(size_t)(c0 + i) * R + r0 + tx] = tile[tx][i];
}

// ================= GEMM 1: P1 = visual @ w_in.T + b_in =================
__global__ __launch_bounds__(256) void k_p1(const float* __restrict__ A,
                                            const float* __restrict__ W,
                                            const float* __restrict__ bias,
                                            float* __restrict__ Cout) {
  __shared__ float As[BK][BM + 4];
  __shared__ float Bs[BK][BN + 4];
  const int tid = threadIdx.x;
  const int m0 = blockIdx.y * BM;
  const int n0 = blockIdx.x * BN;
  const int tx = tid & 15, ty = tid >> 4;
  float acc[8][8];
#pragma unroll
  for (int i = 0; i < 8; ++i)
#pragma unroll
    for (int j = 0; j < 8; ++j) acc[i][j] = 0.f;

  for (int kb = 0; kb < CD; kb += BK) {
#pragma unroll
    for (int p = 0; p < 4; ++p) {
      int r = (tid >> 3) + p * 32;
      int k = tid & 7;
      As[k][r] = A[(size_t)(m0 + r) * CD + kb + k];
      Bs[k][r] = W[(size_t)(n0 + r) * CD + kb + k];
    }
    __syncthreads();
#pragma unroll
    for (int kk = 0; kk < BK; ++kk) {
      float av[8], bv[8];
      *(float4*)&av[0] = *(const float4*)&As[kk][ty * 8];
      *(float4*)&av[4] = *(const float4*)&As[kk][ty * 8 + 4];
      *(float4*)&bv[0] = *(const float4*)&Bs[kk][tx * 8];
      *(float4*)&bv[4] = *(const float4*)&Bs[kk][tx * 8 + 4];
#pragma unroll
      for (int i = 0; i < 8; ++i)
#pragma unroll
        for (int j = 0; j < 8; ++j) acc[i][j] += av[i] * bv[j];
    }
    __syncthreads();
  }
#pragma unroll
  for (int i = 0; i < 8; ++i) {
    int m = m0 + ty * 8 + i;
#pragma unroll
    for (int j = 0; j < 8; ++j) {
      int n = n0 + tx * 8 + j;
      Cout[(size_t)m * CH + n] = acc[i][j] + bias[n];
    }
  }
}

// ================= GEMM 2: M1 = relu(motion @ w_m1p.T + b_m1p) =================
__global__ __launch_bounds__(256) void k_m1(const float* __restrict__ A,
                                            const float* __restrict__ W,
                                            const float* __restrict__ bias,
                                            float* __restrict__ Cout) {
  __shared__ float As[BK][BM + 4];
  __shared__ float Bs[BK][BN + 4];
  const int tid = threadIdx.x;
  const int m0 = blockIdx.y * BM;
  const int n0 = blockIdx.x * BN;
  const int tx = tid & 15, ty = tid >> 4;
  const int frame = (m0 >> 8);         // (b*16 + t)
  const int tfrm = frame & 15;
  float acc[8][8];
#pragma unroll
  for (int i = 0; i < 8; ++i)
#pragma unroll
    for (int j = 0; j < 8; ++j) acc[i][j] = 0.f;

  for (int kb = 0; kb < CD; kb += BK) {
#pragma unroll
    for (int p = 0; p < 4; ++p) {
      int r = (tid >> 3) + p * 32;
      int k = tid & 7;
      float mv = 0.f;
      if (tfrm < 15) {
        float cur = A[(size_t)(m0 + r) * CD + kb + k];
        float nxt = A[(size_t)(m0 + r + 256) * CD + kb + k];
        mv = nxt - cur;
      }
      As[k][r] = mv;
      Bs[k][r] = W[(size_t)(n0 + r) * CD + kb + k];
    }
    __syncthreads();
#pragma unroll
    for (int kk = 0; kk < BK; ++kk) {
      float av[8], bv[8];
      *(float4*)&av[0] = *(const float4*)&As[kk][ty * 8];
      *(float4*)&av[4] = *(const float4*)&As[kk][ty * 8 + 4];
      *(float4*)&bv[0] = *(const float4*)&Bs[kk][tx * 8];
      *(float4*)&bv[4] = *(const float4*)&Bs[kk][tx * 8 + 4];
#pragma unroll
      for (int i = 0; i < 8; ++i)
#pragma unroll
        for (int j = 0; j < 8; ++j) acc[i][j] += av[i] * bv[j];
    }
    __syncthreads();
  }
#pragma unroll
  for (int i = 0; i < 8; ++i) {
    int m = m0 + ty * 8 + i;
#pragma unroll
    for (int j = 0; j < 8; ++j) {
      int n = n0 + tx * 8 + j;
      Cout[(size_t)m * CH + n] = fmaxf(acc[i][j] + bias[n], 0.f);
    }
  }
}

// ================= row stats of P1 for LN =================
__global__ __launch_bounds__(256) void k_rowstats(const float* __restrict__ P1,
                                                  float* __restrict__ st) {
  int row = blockIdx.x * 4 + (threadIdx.x >> 6);
  int lane = threadIdx.x & 63;
  const float* r = P1 + (size_t)row * CH;
  float4 x0 = *(const float4*)&r[lane * 8];
  float4 x1 = *(const float4*)&r[lane * 8 + 4];
  float s = x0.x + x0.y + x0.z + x0.w + x1.x + x1.y + x1.z + x1.w;
  for (int o = 32; o; o >>= 1) s += __shfl_xor(s, o);
  float mean = s * (1.f / CH);
  float d, s2 = 0.f;
  d = x0.x - mean; s2 += d * d; d = x0.y - mean; s2 += d * d;
  d = x0.z - mean; s2 += d * d; d = x0.w - mean; s2 += d * d;
  d = x1.x - mean; s2 += d * d; d = x1.y - mean; s2 += d * d;
  d = x1.z - mean; s2 += d * d; d = x1.w - mean; s2 += d * d;
  for (int o = 32; o; o >>= 1) s2 += __shfl_xor(s2, o);
  if (lane == 0) {
    st[2 * row] = mean;
    st[2 * row + 1] = rsqrtf(s2 * (1.f / CH) + 1e-5f);
  }
}

// ================= GEMM 3: feats = LN(P1)*g+b + 0.5*(M1 @ w_m2p.T + b_m2p), in-place over P1 =================
__global__ __launch_bounds__(256) void k_feats(const float* __restrict__ A,  // M1
                                               const float* __restrict__ W,  // w_m2p
                                               const float* __restrict__ bias,
                                               const float* __restrict__ st,
                                               const float* __restrict__ g_ln,
                                               const float* __restrict__ b_ln,
                                               float* __restrict__ P1inout) {
  __shared__ float As[BK][BM + 4];
  __shared__ float Bs[BK][BN + 4];
  const int tid = threadIdx.x;
  const int m0 = blockIdx.y * BM;
  const int n0 = blockIdx.x * BN;
  const int tx = tid & 15, ty = tid >> 4;
  float acc[8][8];
#pragma unroll
  for (int i = 0; i < 8; ++i)
#pragma unroll
    for (int j = 0; j < 8; ++j) acc[i][j] = 0.f;

  for (int kb = 0; kb < CH; kb += BK) {
#pragma unroll
    for (int p = 0; p < 4; ++p) {
      int r = (tid >> 3) + p * 32;
      int k = tid & 7;
      As[k][r] = A[(size_t)(m0 + r) * CH + kb + k];
      Bs[k][r] = W[(size_t)(n0 + r) * CH + kb + k];
    }
    __syncthreads();
#pragma unroll
    for (int kk = 0; kk < BK; ++kk) {
      float av[8], bv[8];
      *(float4*)&av[0] = *(const float4*)&As[kk][ty * 8];
      *(float4*)&av[4] = *(const float4*)&As[kk][ty * 8 + 4];
      *(float4*)&bv[0] = *(const float4*)&Bs[kk][tx * 8];
      *(float4*)&bv[4] = *(const float4*)&Bs[kk][tx * 8 + 4];
#pragma unroll
      for (int i = 0; i < 8; ++i)
#pragma unroll
        for (int j = 0; j < 8; ++j) acc[i][j] += av[i] * bv[j];
    }
    __syncthreads();
  }
#pragma unroll
  for (int i = 0; i < 8; ++i) {
    int m = m0 + ty * 8 + i;
    float mean = st[2 * m], rstd = st[2 * m + 1];
#pragma unroll
    for (int j = 0; j < 8; ++j) {
      int n = n0 + tx * 8 + j;
      size_t idx = (size_t)m * CH + n;
      float p1v = P1inout[idx];
      float v = (p1v - mean) * rstd * g_ln[n] + b_ln[n] + 0.5f * (acc[i][j] + bias[n]);
      P1inout[idx] = v;
    }
  }
}

// ================= GEMM 4: k|v = feats @ [w_k; w_v].T =================
__global__ __launch_bounds__(256) void k_kv(const float* __restrict__ A,  // feats
                                            const float* __restrict__ Wk,
                                            const float* __restrict__ Wv,
                                            float* __restrict__ kbuf,
                                            float* __restrict__ vbuf) {
  __shared__ float As[BK][BM + 4];
  __shared__ float Bs[BK][BN + 4];
  const int tid = threadIdx.x;
  const int m0 = blockIdx.y * BM;
  const int n0 = blockIdx.x * BN;  // 0..1023
  const int tx = tid & 15, ty = tid >> 4;
  const bool khalf = (n0 < 512);
  const float* W = khalf ? (Wk + (size_t)n0 * CH) : (Wv + (size_t)(n0 - 512) * CH);
  float* Out = khalf ? (kbuf) : (vbuf);
  const int nbase = khalf ? n0 : (n0 - 512);
  float acc[8][8];
#pragma unroll
  for (int i = 0; i < 8; ++i)
#pragma unroll
    for (int j = 0; j < 8; ++j) acc[i][j] = 0.f;

  for (int kb = 0; kb < CH; kb += BK) {
#pragma unroll
    for (int p = 0; p < 4; ++p) {
      int r = (tid >> 3) + p * 32;
      int k = tid & 7;
      As[k][r] = A[(size_t)(m0 + r) * CH + kb + k];
      Bs[k][r] = W[(size_t)r * CH + kb + k];
    }
    __syncthreads();
#pragma unroll
    for (int kk = 0; kk < BK; ++kk) {
      float av[8], bv[8];
      *(float4*)&av[0] = *(const float4*)&As[kk][ty * 8];
      *(float4*)&av[4] = *(const float4*)&As[kk][ty * 8 + 4];
      *(float4*)&bv[0] = *(const float4*)&Bs[kk][tx * 8];
      *(float4*)&bv[4] = *(const float4*)&Bs[kk][tx * 8 + 4];
#pragma unroll
      for (int i = 0; i < 8; ++i)
#pragma unroll
        for (int j = 0; j < 8; ++j) acc[i][j] += av[i] * bv[j];
    }
    __syncthreads();
  }
#pragma unroll
  for (int i = 0; i < 8; ++i) {
    int m = m0 + ty * 8 + i;
#pragma unroll
    for (int j = 0; j < 8; ++j) {
      int n = nbase + tx * 8 + j;
      Out[(size_t)m * CH + n] = acc[i][j];
    }
  }
}

// ================= device-scope grid barrier =================
__device__ inline void gbar(unsigned* bar, int nwg) {
  __syncthreads();
  if (threadIdx.x == 0) {
    __threadfence();
    unsigned g = __hip_atomic_load(&bar[1], __ATOMIC_RELAXED, __HIP_MEMORY_SCOPE_AGENT);
    unsigned a = __hip_atomic_fetch_add(&bar[0], 1u, __ATOMIC_ACQ_REL, __HIP_MEMORY_SCOPE_AGENT);
    if (a == (unsigned)(nwg - 1)) {
      __hip_atomic_store(&bar[0], 0u, __ATOMIC_RELAXED, __HIP_MEMORY_SCOPE_AGENT);
      __hip_atomic_fetch_add(&bar[1], 1u, __ATOMIC_RELEASE, __HIP_MEMORY_SCOPE_AGENT);
    } else {
      while (__hip_atomic_load(&bar[1], __ATOMIC_ACQUIRE, __HIP_MEMORY_SCOPE_AGENT) == g)
        __builtin_amdgcn_s_sleep(2);
    }
    __threadfence();
  }
  __syncthreads();
}

// ================= persistent slot-attention scan =================
__global__ __launch_bounds__(256) void k_scan(float* __restrict__ ws,
                                              const float* __restrict__ b_ih,
                                              const float* __restrict__ b_hh,
                                              const float* __restrict__ g_ls,
                                              const float* __restrict__ b_ls,
                                              const float* __restrict__ g_lm,
                                              const float* __restrict__ b_lm,
                                              const float* __restrict__ b_m1,
                                              const float* __restrict__ b_m2,
                                              float* __restrict__ spf,
                                              float* __restrict__ att,
                                              int nwg) {
  const float* kbuf = ws + OFS_M1;
  const float* vbuf = ws + OFS_V;
  const float* wqT  = ws + OFS_WQT;
  const float* whhT = ws + OFS_WHHT;
  const float* wihT = ws + OFS_WIHT;
  const float* wm1T = ws + OFS_WM1T;
  const float* wm2T = ws + OFS_WM2T;
  float* slots = ws + OFS_SLOTS;
  float* qb    = ws + OFS_Q;
  float* ghb   = ws + OFS_GH;
  float* attnb = ws + OFS_ATTN;
  float* Ub    = ws + OFS_U;
  float* Zb    = ws + OFS_Z;
  float* hb    = ws + OFS_H;
  float* yb    = ws + OFS_Y;
  unsigned* bar = (unsigned*)(ws + OFS_BAR);

  const int tid = threadIdx.x;
  const int gt = blockIdx.x * 256 + tid;
  const int nth = nwg * 256;
  const int wv = gt >> 6;
  const int lane = tid & 63;
  const int nwv = nth >> 6;
  const float scale = 0.04419417382415922f;  // 512^-0.5

  for (int t = 0; t < CT; ++t) {
    for (int it = 0; it < NITER; ++it) {
      // ---- P1: q = LN(slots)@w_q.T ; gh = slots@w_hh.T + b_hh ----
      for (int job = wv; job < 768; job += nwv) {
        if (job < 192) {
          int r = job >> 3, ch = job & 7;
          const float* srow = slots + r * CH;
          float s = 0.f;
          for (int u = lane; u < CH; u += 64) s += srow[u];
          for (int o = 32; o; o >>= 1) s += __shfl_xor(s, o);
          float mean = s * (1.f / CH);
          float s2 = 0.f;
          for (int u = lane; u < CH; u += 64) { float d = srow[u] - mean; s2 += d * d; }
          for (int o = 32; o; o >>= 1) s2 += __shfl_xor(s2, o);
          float rstd = rsqrtf(s2 * (1.f / CH) + 1e-5f);
          int j = ch * 64 + lane;
          float acc = 0.f;
          for (int h = 0; h < CH; ++h) {
            float xn = (srow[h] - mean) * rstd * g_ls[h] + b_ls[h];
            acc += xn * wqT[h * CH + j];
          }
          qb[r * CH + j] = acc;
        } else {
          int j2 = job - 192;
          int r = j2 / 24, ch = j2 % 24;
          int j = ch * 64 + lane;
          const float* srow = slots + r * CH;
          float acc = b_hh[j];
          for (int h = 0; h < CH; ++h) acc += srow[h] * whhT[h * CH3 + j];
          ghb[r * CH3 + j] = acc;
        }
      }
      gbar(bar, nwg);
      // ---- P2a: logits -> softmax over s -> attn (+att output) ----
      for (int job = wv; job < CB * CN; job += nwv) {
        int b = job >> 8, n = job & 255;
        const float* krow = kbuf + ((size_t)((b * CT + t) * CN + n)) * CH;
        const float* q0 = qb + (b * 3 + 0) * CH;
        const float* q1 = q0 + CH;
        const float* q2 = q1 + CH;
        float p0 = 0.f, p1 = 0.f, p2 = 0.f;
        for (int u = 0; u < 8; ++u) {
          int h = lane * 8 + u;
          float kk = krow[h];
          p0 += q0[h] * kk; p1 += q1[h] * kk; p2 += q2[h] * kk;
        }
        for (int o = 32; o; o >>= 1) {
          p0 += __shfl_xor(p0, o); p1 += __shfl_xor(p1, o); p2 += __shfl_xor(p2, o);
        }
        p0 *= scale; p1 *= scale; p2 *= scale;
        float mx = fmaxf(p0, fmaxf(p1, p2));
        float e0 = expf(p0 - mx), e1 = expf(p1 - mx), e2 = expf(p2 - mx);
        float inv = 1.f / (e0 + e1 + e2);
        if (lane < 3) {
          float a = (lane == 0 ? e0 : (lane == 1 ? e1 : e2)) * inv;
          attnb[(b * 3 + lane) * CN + n] = a;
          if (it == NITER - 1)
            att[((size_t)(b * CT + t) * CS + lane) * CN + n] = a;
        }
      }
      gbar(bar, nwg);
      // ---- P2b: U = sum_n attn*v ; Z = sum_n attn ----
      for (int e = gt; e < CBS * CH + CBS; e += nth) {
        if (e < CBS * CH) {
          int r = e >> 9, j = e & 511;
          int b = r / 3;
          const float* arow = attnb + r * CN;
          const float* vb2 = vbuf + ((size_t)((b * CT + t) * CN)) * CH + j;
          float acc = 0.f;
          for (int n = 0; n < CN; ++n) acc += arow[n] * vb2[(size_t)n * CH];
          Ub[e] = acc;
        } else {
          int r = e - CBS * CH;
          const float* arow = attnb + r * CN;
          float z = 0.f;
          for (int n = 0; n < CN; ++n) z += arow[n];
          Zb[r] = z;
        }
      }
      gbar(bar, nwg);
      // ---- P3: GRU -> h ----
      for (int e = gt; e < CBS * CH; e += nth) {
        int r = e >> 9, j = e & 511;
        float invZ = 1.f / (Zb[r] + 1e-8f);
        const float* urow = Ub + r * CH;
        float gr = b_ih[j], gz = b_ih[CH + j], gn = b_ih[2 * CH + j];
        for (int h = 0; h < CH; ++h) {
          float u = urow[h] * invZ;
          const float* wrow = wihT + (size_t)h * CH3;
          gr += u * wrow[j];
          gz += u * wrow[CH + j];
          gn += u * wrow[2 * CH + j];
        }
        float ghr = ghb[r * CH3 + j];
        float ghz = ghb[r * CH3 + CH + j];
        float ghn = ghb[r * CH3 + 2 * CH + j];
        float rr = 1.f / (1.f + expf(-(gr + ghr)));
        float zz = 1.f / (1.f + expf(-(gz + ghz)));
        float nn = tanhf(gn + rr * ghn);
        hb[e] = (1.f - zz) * nn + zz * slots[e];
      }
      gbar(bar, nwg);
      // ---- P4: y = gelu(LN(h)@w_mlp1.T + b_mlp1) ----
      for (int job = wv; job < 384; job += nwv) {
        int r = job >> 4, ch = job & 15;
        const float* hrow = hb + r * CH;
        float s = 0.f;
        for (int u = lane; u < CH; u += 64) s += hrow[u];
        for (int o = 32; o; o >>= 1) s += __shfl_xor(s, o);
        float mean = s * (1.f / CH);
        float s2 = 0.f;
        for (int u = lane; u < CH; u += 64) { float d = hrow[u] - mean; s2 += d * d; }
        for (int o = 32; o; o >>= 1) s2 += __shfl_xor(s2, o);
        float rstd = rsqrtf(s2 * (1.f / CH) + 1e-5f);
        int c = ch * 64 + lane;
        float acc = b_m1[c];
        for (int h = 0; h < CH; ++h) {
          float xn = (hrow[h] - mean) * rstd * g_lm[h] + b_lm[h];
          acc += xn * wm1T[h * CH2 + c];
        }
        float g = 0.5f * acc * (1.f + erff(acc * 0.70710678118654752f));
        yb[r * CH2 + c] = g;
      }
      gbar(bar, nwg);
      // ---- P5: slots' = h + y@w_mlp2.T + b_mlp2 (+spf output) ----
      for (int job = wv; job < 192; job += nwv) {
        int r = job >> 3, ch = job & 7;
        int j = ch * 64 + lane;
        const float* yrow = yb + r * CH2;
        float acc = b_m2[j];
        for (int c = 0; c < CH2; ++c) acc += yrow[c] * wm2T[c * CH + j];
        float sn = hb[r * CH + j] + acc;
        slots[r * CH + j] = sn;
        if (it == NITER - 1) {
          int b = r / 3, s5 = r % 3;
          spf[((size_t)(b * CT + t) * CS + s5) * CH + j] = sn;
        }
      }
      gbar(bar, nwg);
    }
  }
}

// ================= temporal attention: qkv projection =================
__global__ __launch_bounds__(256) void k_tproj(const float* __restrict__ spf,
                                               const float* __restrict__ ws_c,
                                               const float* __restrict__ b_tq,
                                               const float* __restrict__ b_tk,
                                               const float* __restrict__ b_tv,
                                               float* __restrict__ tqkv) {
  __shared__ float xr[CH];
  int row = blockIdx.x;  // bs*16 + t
  int bs = row >> 4, t = row & 15;
  int b = bs / 3, s = bs % 3;
  const float* x = spf + ((size_t)(b * CT + t) * CS + s) * CH;
  for (int i = threadIdx.x; i < CH; i += 256) xr[i] = x[i];
  __syncthreads();
  for (int p = 0; p < 6; ++p) {
    int j = p * 256 + threadIdx.x;
    const float* wT; const float* bb; int jj;
    if (j < 512)      { wT = ws_c + OFS_WTQT; bb = b_tq; jj = j; }
    else if (j < 1024){ wT = ws_c + OFS_WTKT; bb = b_tk; jj = j - 512; }
    else              { wT = ws_c + OFS_WTVT; bb = b_tv; jj = j - 1024; }
    float acc = bb[jj];
    for (int h = 0; h < CH; ++h) acc += xr[h] * wT[h * CH + jj];
    tqkv[(size_t)row * CH3 + j] = acc;
  }
}

// ================= temporal attention: per (track, head) =================
__global__ __launch_bounds__(64) void k_tattn(const float* __restrict__ tqkv,
                                              float* __restrict__ ob) {
  __shared__ float qs[16][68], ks[16][68], vs[16][68], sc[16][20];
  int bs = blockIdx.x >> 3, hh = blockIdx.x & 7;
  int lane = threadIdx.x;
  for (int i = 0; i < 16; ++i) {
    const float* base = tqkv + (size_t)(bs * 16 + i) * CH3 + hh * 64;
    qs[i][lane] = base[lane];
    ks[i][lane] = base[512 + lane];
    vs[i][lane] = base[1024 + lane];
  }
  __syncthreads();
  for (int u = 0; u < 4; ++u) {
    int ee = u * 64 + lane;
    int i = ee >> 4, j = ee & 15;
    float acc = 0.f;
    for (int d = 0; d < 64; ++d) acc += qs[i][d] * ks[j][d];
    sc[i][j] = acc * 0.125f;  // 1/sqrt(64)
  }
  __syncthreads();
  if (lane < 16) {
    float mx = -1e30f;
    for (int j = 0; j < 16; ++j) mx = fmaxf(mx, sc[lane][j]);
    float sum = 0.f;
    for (int j = 0; j < 16; ++j) { float ev = expf(sc[lane][j] - mx); sc[lane][j] = ev; sum += ev; }
    float inv = 1.f / sum;
    for (int j = 0; j < 16; ++j) sc[lane][j] *= inv;
  }
  __syncthreads();
  for (int i = 0; i < 16; ++i) {
    float acc = 0.f;
    for (int j = 0; j < 16; ++j) acc += sc[i][j] * vs[j][lane];
    ob[(size_t)(bs * 16 + i) * CH + hh * 64 + lane] = acc;
  }
}

// ================= temporal out-proj + residual + LN + mean =================
__global__ __launch_bounds__(256) void k_tout(const float* __restrict__ ob,
                                              const float* __restrict__ spf,
                                              const float* __restrict__ ws_c,
                                              const float* __restrict__ b_to,
                                              const float* __restrict__ g_lt,
                                              const float* __restrict__ b_lt,
                                              float* __restrict__ agg) {
  __shared__ float orow[CH], rrow[CH], red[8];
  int row = blockIdx.x;
  int bs = row >> 4, t = row & 15;
  int b = bs / 3, s = bs % 3;
  const float* x = spf + ((size_t)(b * CT + t) * CS + s) * CH;
  const float* o = ob + (size_t)row * CH;
  for (int i = threadIdx.x; i < CH; i += 256) orow[i] = o[i];
  __syncthreads();
  const float* wto = ws_c + OFS_WTOT;
  for (int p = 0; p < 2; ++p) {
    int j = p * 256 + threadIdx.x;
    float acc = b_to[j];
    for (int c = 0; c < CH; ++c) acc += orow[c] * wto[c * CH + j];
    rrow[j] = acc + x[j];
  }
  __syncthreads();
  float part = rrow[threadIdx.x] + rrow[threadIdx.x + 256];
  for (int o2 = 32; o2; o2 >>= 1) part += __shfl_xor(part, o2);
  if ((threadIdx.x & 63) == 0) red[threadIdx.x >> 6] = part;
  __syncthreads();
  float mean = (red[0] + red[1] + red[2] + red[3]) * (1.f / CH);
  float d0 = rrow[threadIdx.x] - mean, d1 = rrow[threadIdx.x + 256] - mean;
  float p2 = d0 * d0 + d1 * d1;
  for (int o2 = 32; o2; o2 >>= 1) p2 += __shfl_xor(p2, o2);
  __syncthreads();
  if ((threadIdx.x & 63) == 0) red[(threadIdx.x >> 6) + 4] = p2;
  __syncthreads();
  float rstd = rsqrtf((red[4] + red[5] + red[6] + red[7]) * (1.f / CH) + 1e-5f);
  for (int p = 0; p < 2; ++p) {
    int j = p * 256 + threadIdx.x;
    float xt = (rrow[j] - mean) * rstd * g_lt[j] + b_lt[j];
    atomicAdd(&agg[(size_t)bs * CH + j], xt * (1.f / CT));
  }
}

// ================= launch =================
extern "C" void kernel_launch(void* const* d_in, const int* in_sizes, int n_in,
                              void* d_out, int out_size, void* d_ws, size_t ws_size,
                              hipStream_t stream) {
  (void)in_sizes; (void)n_in; (void)out_size; (void)ws_size;
  const float* visual = (const float*)d_in[0];
  const float* noise  = (const float*)d_in[1];
  const float* mu     = (const float*)d_in[2];
  const float* sigma  = (const float*)d_in[3];
  const float* w_in   = (const float*)d_in[4];
  const float* b_in   = (const float*)d_in[5];
  const float* g_lin  = (const float*)d_in[6];
  const float* b_lin  = (const float*)d_in[7];
  const float* w_m1p  = (const float*)d_in[8];
  const float* b_m1p  = (const float*)d_in[9];
  const float* w_m2p  = (const float*)d_in[10];
  const float* b_m2p  = (const float*)d_in[11];
  const float* w_q    = (const float*)d_in[12];
  const float* w_k    = (const float*)d_in[13];
  const float* w_v    = (const float*)d_in[14];
  const float* w_ih   = (const float*)d_in[15];
  const float* w_hh   = (const float*)d_in[16];
  const float* b_ih   = (const float*)d_in[17];
  const float* b_hh   = (const float*)d_in[18];
  const float* g_ls   = (const float*)d_in[19];
  const float* b_ls   = (const float*)d_in[20];
  const float* g_lm   = (const float*)d_in[21];
  const float* b_lm   = (const float*)d_in[22];
  const float* w_mlp1 = (const float*)d_in[23];
  const float* b_mlp1 = (const float*)d_in[24];
  const float* w_mlp2 = (const float*)d_in[25];
  const float* b_mlp2 = (const float*)d_in[26];
  const float* w_tq   = (const float*)d_in[27];
  const float* b_tq   = (const float*)d_in[28];
  const float* w_tk   = (const float*)d_in[29];
  const float* b_tk   = (const float*)d_in[30];
  const float* w_tv   = (const float*)d_in[31];
  const float* b_tv   = (const float*)d_in[32];
  const float* w_to   = (const float*)d_in[33];
  const float* b_to   = (const float*)d_in[34];
  const float* g_lt   = (const float*)d_in[35];
  const float* b_lt   = (const float*)d_in[36];

  float* ws  = (float*)d_ws;
  float* out = (float*)d_out;
  float* spf = out + 12288;
  float* att = out + 12288 + 196608;

  hipLaunchKernelGGL(k_init, dim3(48), dim3(256), 0, stream, noise, mu, sigma, ws, out);
  hipLaunchKernelGGL(k_transpose, dim3(32, 48, 9), dim3(256), 0, stream,
                     w_q, w_hh, w_ih, w_mlp1, w_mlp2, w_to, w_tq, w_tk, w_tv, ws);
  // Stage 1
  hipLaunchKernelGGL(k_p1, dim3(4, 256), dim3(256), 0, stream,
                     visual, w_in, b_in, ws + OFS_P1);
  hipLaunchKernelGGL(k_rowstats, dim3(CM / 4), dim3(256), 0, stream,
                     ws + OFS_P1, ws + OFS_ST);
  hipLaunchKernelGGL(k_m1, dim3(4, 256), dim3(256), 0, stream,
                     visual, w_m1p, b_m1p, ws + OFS_M1);
  hipLaunchKernelGGL(k_feats, dim3(4, 256), dim3(256), 0, stream,
                     ws + OFS_M1, w_m2p, b_m2p, ws + OFS_ST, g_lin, b_lin, ws + OFS_P1);
  hipLaunchKernelGGL(k_kv, dim3(8, 256), dim3(256), 0, stream,
                     ws + OFS_P1, w_k, w_v, ws + OFS_M1, ws + OFS_V);
  // Stage 2: persistent scan (96 co-resident WGs, custom device barrier)
  hipLaunchKernelGGL(k_scan, dim3(96), dim3(256), 0, stream,
                     ws, b_ih, b_hh, g_ls, b_ls, g_lm, b_lm, b_mlp1, b_mlp2,
                     spf, att, 96);
  // Stage 3: temporal attention
  hipLaunchKernelGGL(k_tproj, dim3(384), dim3(256), 0, stream,
                     spf, ws, b_tq, b_tk, b_tv, ws + OFS_TQKV);
  hipLaunchKernelGGL(k_tattn, dim3(192), dim3(64), 0, stream,
                     ws + OFS_TQKV, ws + OFS_TO);
  hipLaunchKernelGGL(k_tout, dim3(384), dim3(256), 0, stream,
                     ws + OFS_TO, spf, ws, b_to, g_lt, b_lt, out);
}

// Round 2
// 12563.074 us; speedup vs baseline: 1.1576x; 1.1576x over previous
//
#include <hip/hip_runtime.h>
#include <math.h>

// ---------------- problem constants ----------------
#define CB 8
#define CT 16
#define CN 256
#define CD 1280
#define CH 512
#define CS 3
#define CM (CB*CT*CN)      // 32768 rows
#define CBS (CB*CS)        // 24
#define CH3 (3*CH)         // 1536
#define CH2 (2*CH)         // 1024
#define NITER 3

// ---------------- workspace layout (float offsets) ----------------
#define OFS_P1   0ULL                       // P1, later feats (in-place): CM*CH
#define OFS_M1   16777216ULL                // M1, later k_buf (overwrite): CM*CH
#define OFS_V    33554432ULL                // v_buf: CM*CH
#define OFS_ST   50331648ULL                // rowstats: CM*2
#define OFS_WQT  50397184ULL                // 512*512
#define OFS_WHHT (OFS_WQT + 262144ULL)      // 512*1536
#define OFS_WIHT (OFS_WHHT + 786432ULL)     // 512*1536
#define OFS_WM1T (OFS_WIHT + 786432ULL)     // 512*1024
#define OFS_WM2T (OFS_WM1T + 524288ULL)     // 1024*512
#define OFS_WTOT (OFS_WM2T + 524288ULL)     // 512*512
#define OFS_WTQT (OFS_WTOT + 262144ULL)
#define OFS_WTKT (OFS_WTQT + 262144ULL)
#define OFS_WTVT (OFS_WTKT + 262144ULL)
#define OFS_SLOTS (OFS_WTVT + 262144ULL)    // 24*512
#define OFS_Q    (OFS_SLOTS + 12288ULL)
#define OFS_GH   (OFS_Q + 12288ULL)         // 24*1536 (unused now)
#define OFS_ATTN (OFS_GH + 36864ULL)        // 24*256
#define OFS_U    (OFS_ATTN + 6144ULL)       // 24*512
#define OFS_Z    (OFS_U + 12288ULL)         // 32 (unused now)
#define OFS_H    (OFS_Z + 32ULL)            // 24*512
#define OFS_Y    (OFS_H + 12288ULL)         // 24*1024
#define OFS_TQKV (OFS_Y + 24576ULL)         // 384*1536
#define OFS_TO   (OFS_TQKV + 589824ULL)     // 384*512
#define OFS_BAR  (OFS_TO + 196608ULL)       // barrier counters (uints)

// ---------------- GEMM tiling ----------------
#define BM 128
#define BN 128
#define BK 8

// ================= init: slots0, zero agg + barrier =================
__global__ __launch_bounds__(256) void k_init(const float* __restrict__ noise,
                                              const float* __restrict__ mu,
                                              const float* __restrict__ sigma,
                                              float* __restrict__ ws,
                                              float* __restrict__ out) {
  int i = blockIdx.x * 256 + threadIdx.x;
  if (i < 12288) {
    int sj = i % 1536;  // (s,h) index into mu/sigma [1,3,512]
    ws[OFS_SLOTS + i] = mu[sj] + sigma[sj] * noise[i];
    out[i] = 0.0f;      // zero slots_agg accumulation region
  }
  if (i < 16) {
    unsigned* bar = (unsigned*)(ws + OFS_BAR);
    bar[i] = 0u;
  }
}

// ================= weight transposes (k-major) for coalesced GEMV phases =================
__global__ __launch_bounds__(256) void k_transpose(const float* __restrict__ w_q,
                                                   const float* __restrict__ w_hh,
                                                   const float* __restrict__ w_ih,
                                                   const float* __restrict__ w_mlp1,
                                                   const float* __restrict__ w_mlp2,
                                                   const float* __restrict__ w_to,
                                                   const float* __restrict__ w_tq,
                                                   const float* __restrict__ w_tk,
                                                   const float* __restrict__ w_tv,
                                                   float* __restrict__ ws) {
  const float* src; float* dst; int R, C;
  switch (blockIdx.z) {
    case 0: src = w_q;    dst = ws + OFS_WQT;  R = 512;  C = 512;  break;
    case 1: src = w_hh;   dst = ws + OFS_WHHT; R = 1536; C = 512;  break;
    case 2: src = w_ih;   dst = ws + OFS_WIHT; R = 1536; C = 512;  break;
    case 3: src = w_mlp1; dst = ws + OFS_WM1T; R = 1024; C = 512;  break;
    case 4: src = w_mlp2; dst = ws + OFS_WM2T; R = 512;  C = 1024; break;
    case 5: src = w_to;   dst = ws + OFS_WTOT; R = 512;  C = 512;  break;
    case 6: src = w_tq;   dst = ws + OFS_WTQT; R = 512;  C = 512;  break;
    case 7: src = w_tk;   dst = ws + OFS_WTKT; R = 512;  C = 512;  break;
    default: src = w_tv;  dst = ws + OFS_WTVT; R = 512;  C = 512;  break;
  }
  int r0 = blockIdx.y * 32, c0 = blockIdx.x * 32;
  if (r0 >= R || c0 >= C) return;
  __shared__ float tile[32][33];
  int tx = threadIdx.x & 31, ty = threadIdx.x >> 5;  // 32 x 8
  for (int i = ty; i < 32; i += 8)
    tile[i][tx] = src[(size_t)(r0 + i) * C + c0 + tx];
  __syncthreads();
  // dst[c*R + r] = src[r*C + c]  -> dst is [in_dim k][out_col]
  for (int i = ty; i < 32; i += 8)
    dst[(size_t)(c0 + i) * R + r0 + tx] = tile[tx][i];
}

// ================= GEMM 1: P1 = visual @ w_in.T + b_in =================
__global__ __launch_bounds__(256) void k_p1(const float* __restrict__ A,
                                            const float* __restrict__ W,
                                            const float* __restrict__ bias,
                                            float* __restrict__ Cout) {
  __shared__ float As[BK][BM + 4];
  __shared__ float Bs[BK][BN + 4];
  const int tid = threadIdx.x;
  const int m0 = blockIdx.y * BM;
  const int n0 = blockIdx.x * BN;
  const int tx = tid & 15, ty = tid >> 4;
  float acc[8][8];
#pragma unroll
  for (int i = 0; i < 8; ++i)
#pragma unroll
    for (int j = 0; j < 8; ++j) acc[i][j] = 0.f;

  for (int kb = 0; kb < CD; kb += BK) {
#pragma unroll
    for (int p = 0; p < 4; ++p) {
      int r = (tid >> 3) + p * 32;
      int k = tid & 7;
      As[k][r] = A[(size_t)(m0 + r) * CD + kb + k];
      Bs[k][r] = W[(size_t)(n0 + r) * CD + kb + k];
    }
    __syncthreads();
#pragma unroll
    for (int kk = 0; kk < BK; ++kk) {
      float av[8], bv[8];
      *(float4*)&av[0] = *(const float4*)&As[kk][ty * 8];
      *(float4*)&av[4] = *(const float4*)&As[kk][ty * 8 + 4];
      *(float4*)&bv[0] = *(const float4*)&Bs[kk][tx * 8];
      *(float4*)&bv[4] = *(const float4*)&Bs[kk][tx * 8 + 4];
#pragma unroll
      for (int i = 0; i < 8; ++i)
#pragma unroll
        for (int j = 0; j < 8; ++j) acc[i][j] += av[i] * bv[j];
    }
    __syncthreads();
  }
#pragma unroll
  for (int i = 0; i < 8; ++i) {
    int m = m0 + ty * 8 + i;
#pragma unroll
    for (int j = 0; j < 8; ++j) {
      int n = n0 + tx * 8 + j;
      Cout[(size_t)m * CH + n] = acc[i][j] + bias[n];
    }
  }
}

// ================= GEMM 2: M1 = relu(motion @ w_m1p.T + b_m1p) =================
__global__ __launch_bounds__(256) void k_m1(const float* __restrict__ A,
                                            const float* __restrict__ W,
                                            const float* __restrict__ bias,
                                            float* __restrict__ Cout) {
  __shared__ float As[BK][BM + 4];
  __shared__ float Bs[BK][BN + 4];
  const int tid = threadIdx.x;
  const int m0 = blockIdx.y * BM;
  const int n0 = blockIdx.x * BN;
  const int tx = tid & 15, ty = tid >> 4;
  const int frame = (m0 >> 8);         // (b*16 + t)
  const int tfrm = frame & 15;
  float acc[8][8];
#pragma unroll
  for (int i = 0; i < 8; ++i)
#pragma unroll
    for (int j = 0; j < 8; ++j) acc[i][j] = 0.f;

  for (int kb = 0; kb < CD; kb += BK) {
#pragma unroll
    for (int p = 0; p < 4; ++p) {
      int r = (tid >> 3) + p * 32;
      int k = tid & 7;
      float mv = 0.f;
      if (tfrm < 15) {
        float cur = A[(size_t)(m0 + r) * CD + kb + k];
        float nxt = A[(size_t)(m0 + r + 256) * CD + kb + k];
        mv = nxt - cur;
      }
      As[k][r] = mv;
      Bs[k][r] = W[(size_t)(n0 + r) * CD + kb + k];
    }
    __syncthreads();
#pragma unroll
    for (int kk = 0; kk < BK; ++kk) {
      float av[8], bv[8];
      *(float4*)&av[0] = *(const float4*)&As[kk][ty * 8];
      *(float4*)&av[4] = *(const float4*)&As[kk][ty * 8 + 4];
      *(float4*)&bv[0] = *(const float4*)&Bs[kk][tx * 8];
      *(float4*)&bv[4] = *(const float4*)&Bs[kk][tx * 8 + 4];
#pragma unroll
      for (int i = 0; i < 8; ++i)
#pragma unroll
        for (int j = 0; j < 8; ++j) acc[i][j] += av[i] * bv[j];
    }
    __syncthreads();
  }
#pragma unroll
  for (int i = 0; i < 8; ++i) {
    int m = m0 + ty * 8 + i;
#pragma unroll
    for (int j = 0; j < 8; ++j) {
      int n = n0 + tx * 8 + j;
      Cout[(size_t)m * CH + n] = fmaxf(acc[i][j] + bias[n], 0.f);
    }
  }
}

// ================= row stats of P1 for LN =================
__global__ __launch_bounds__(256) void k_rowstats(const float* __restrict__ P1,
                                                  float* __restrict__ st) {
  int row = blockIdx.x * 4 + (threadIdx.x >> 6);
  int lane = threadIdx.x & 63;
  const float* r = P1 + (size_t)row * CH;
  float4 x0 = *(const float4*)&r[lane * 8];
  float4 x1 = *(const float4*)&r[lane * 8 + 4];
  float s = x0.x + x0.y + x0.z + x0.w + x1.x + x1.y + x1.z + x1.w;
  for (int o = 32; o; o >>= 1) s += __shfl_xor(s, o);
  float mean = s * (1.f / CH);
  float d, s2 = 0.f;
  d = x0.x - mean; s2 += d * d; d = x0.y - mean; s2 += d * d;
  d = x0.z - mean; s2 += d * d; d = x0.w - mean; s2 += d * d;
  d = x1.x - mean; s2 += d * d; d = x1.y - mean; s2 += d * d;
  d = x1.z - mean; s2 += d * d; d = x1.w - mean; s2 += d * d;
  for (int o = 32; o; o >>= 1) s2 += __shfl_xor(s2, o);
  if (lane == 0) {
    st[2 * row] = mean;
    st[2 * row + 1] = rsqrtf(s2 * (1.f / CH) + 1e-5f);
  }
}

// ================= GEMM 3: feats = LN(P1)*g+b + 0.5*(M1 @ w_m2p.T + b_m2p), in-place over P1 =================
__global__ __launch_bounds__(256) void k_feats(const float* __restrict__ A,  // M1
                                               const float* __restrict__ W,  // w_m2p
                                               const float* __restrict__ bias,
                                               const float* __restrict__ st,
                                               const float* __restrict__ g_ln,
                                               const float* __restrict__ b_ln,
                                               float* __restrict__ P1inout) {
  __shared__ float As[BK][BM + 4];
  __shared__ float Bs[BK][BN + 4];
  const int tid = threadIdx.x;
  const int m0 = blockIdx.y * BM;
  const int n0 = blockIdx.x * BN;
  const int tx = tid & 15, ty = tid >> 4;
  float acc[8][8];
#pragma unroll
  for (int i = 0; i < 8; ++i)
#pragma unroll
    for (int j = 0; j < 8; ++j) acc[i][j] = 0.f;

  for (int kb = 0; kb < CH; kb += BK) {
#pragma unroll
    for (int p = 0; p < 4; ++p) {
      int r = (tid >> 3) + p * 32;
      int k = tid & 7;
      As[k][r] = A[(size_t)(m0 + r) * CH + kb + k];
      Bs[k][r] = W[(size_t)(n0 + r) * CH + kb + k];
    }
    __syncthreads();
#pragma unroll
    for (int kk = 0; kk < BK; ++kk) {
      float av[8], bv[8];
      *(float4*)&av[0] = *(const float4*)&As[kk][ty * 8];
      *(float4*)&av[4] = *(const float4*)&As[kk][ty * 8 + 4];
      *(float4*)&bv[0] = *(const float4*)&Bs[kk][tx * 8];
      *(float4*)&bv[4] = *(const float4*)&Bs[kk][tx * 8 + 4];
#pragma unroll
      for (int i = 0; i < 8; ++i)
#pragma unroll
        for (int j = 0; j < 8; ++j) acc[i][j] += av[i] * bv[j];
    }
    __syncthreads();
  }
#pragma unroll
  for (int i = 0; i < 8; ++i) {
    int m = m0 + ty * 8 + i;
    float mean = st[2 * m], rstd = st[2 * m + 1];
#pragma unroll
    for (int j = 0; j < 8; ++j) {
      int n = n0 + tx * 8 + j;
      size_t idx = (size_t)m * CH + n;
      float p1v = P1inout[idx];
      float v = (p1v - mean) * rstd * g_ln[n] + b_ln[n] + 0.5f * (acc[i][j] + bias[n]);
      P1inout[idx] = v;
    }
  }
}

// ================= GEMM 4: k|v = feats @ [w_k; w_v].T =================
__global__ __launch_bounds__(256) void k_kv(const float* __restrict__ A,  // feats
                                            const float* __restrict__ Wk,
                                            const float* __restrict__ Wv,
                                            float* __restrict__ kbuf,
                                            float* __restrict__ vbuf) {
  __shared__ float As[BK][BM + 4];
  __shared__ float Bs[BK][BN + 4];
  const int tid = threadIdx.x;
  const int m0 = blockIdx.y * BM;
  const int n0 = blockIdx.x * BN;  // 0..1023
  const int tx = tid & 15, ty = tid >> 4;
  const bool khalf = (n0 < 512);
  const float* W = khalf ? (Wk + (size_t)n0 * CH) : (Wv + (size_t)(n0 - 512) * CH);
  float* Out = khalf ? (kbuf) : (vbuf);
  const int nbase = khalf ? n0 : (n0 - 512);
  float acc[8][8];
#pragma unroll
  for (int i = 0; i < 8; ++i)
#pragma unroll
    for (int j = 0; j < 8; ++j) acc[i][j] = 0.f;

  for (int kb = 0; kb < CH; kb += BK) {
#pragma unroll
    for (int p = 0; p < 4; ++p) {
      int r = (tid >> 3) + p * 32;
      int k = tid & 7;
      As[k][r] = A[(size_t)(m0 + r) * CH + kb + k];
      Bs[k][r] = W[(size_t)r * CH + kb + k];
    }
    __syncthreads();
#pragma unroll
    for (int kk = 0; kk < BK; ++kk) {
      float av[8], bv[8];
      *(float4*)&av[0] = *(const float4*)&As[kk][ty * 8];
      *(float4*)&av[4] = *(const float4*)&As[kk][ty * 8 + 4];
      *(float4*)&bv[0] = *(const float4*)&Bs[kk][tx * 8];
      *(float4*)&bv[4] = *(const float4*)&Bs[kk][tx * 8 + 4];
#pragma unroll
      for (int i = 0; i < 8; ++i)
#pragma unroll
        for (int j = 0; j < 8; ++j) acc[i][j] += av[i] * bv[j];
    }
    __syncthreads();
  }
#pragma unroll
  for (int i = 0; i < 8; ++i) {
    int m = m0 + ty * 8 + i;
#pragma unroll
    for (int j = 0; j < 8; ++j) {
      int n = nbase + tx * 8 + j;
      Out[(size_t)m * CH + n] = acc[i][j];
    }
  }
}

// ================= device-scope grid barrier =================
__device__ inline void gbar(unsigned* bar, int nwg) {
  __syncthreads();
  if (threadIdx.x == 0) {
    __threadfence();
    unsigned g = __hip_atomic_load(&bar[1], __ATOMIC_RELAXED, __HIP_MEMORY_SCOPE_AGENT);
    unsigned a = __hip_atomic_fetch_add(&bar[0], 1u, __ATOMIC_ACQ_REL, __HIP_MEMORY_SCOPE_AGENT);
    if (a == (unsigned)(nwg - 1)) {
      __hip_atomic_store(&bar[0], 0u, __ATOMIC_RELAXED, __HIP_MEMORY_SCOPE_AGENT);
      __hip_atomic_fetch_add(&bar[1], 1u, __ATOMIC_RELEASE, __HIP_MEMORY_SCOPE_AGENT);
    } else {
      while (__hip_atomic_load(&bar[1], __ATOMIC_ACQUIRE, __HIP_MEMORY_SCOPE_AGENT) == g)
        __builtin_amdgcn_s_sleep(2);
    }
    __threadfence();
  }
  __syncthreads();
}

// ================= persistent slot-attention scan (output-sliced, L2-resident weights) =================
// Grid: 128 WGs x 384 threads. WG w: rg=w>>5 (rows rg*6..+6), jg=w&31 (16-wide col slice,
// 64B aligned so each WG's weight slice stays hot in its XCD's L2 across all 288 phases).
__global__ __launch_bounds__(384) void k_scan(float* __restrict__ ws,
                                              const float* __restrict__ b_ih,
                                              const float* __restrict__ b_hh,
                                              const float* __restrict__ g_ls,
                                              const float* __restrict__ b_ls,
                                              const float* __restrict__ g_lm,
                                              const float* __restrict__ b_lm,
                                              const float* __restrict__ b_m1,
                                              const float* __restrict__ b_m2,
                                              float* __restrict__ spf,
                                              float* __restrict__ att,
                                              int nwg) {
  const float* kbuf = ws + OFS_M1;
  const float* vbuf = ws + OFS_V;
  const float* wqT  = ws + OFS_WQT;   // [k=512][c=512]
  const float* whhT = ws + OFS_WHHT;  // [k=512][c=1536]
  const float* wihT = ws + OFS_WIHT;  // [k=512][c=1536]
  const float* wm1T = ws + OFS_WM1T;  // [k=512][c=1024]
  const float* wm2T = ws + OFS_WM2T;  // [k=1024][c=512]
  float* slots = ws + OFS_SLOTS;
  float* qb    = ws + OFS_Q;
  float* attnb = ws + OFS_ATTN;
  float* Ub    = ws + OFS_U;
  float* hb    = ws + OFS_H;
  float* yb    = ws + OFS_Y;
  unsigned* bar = (unsigned*)(ws + OFS_BAR);

  const int w   = blockIdx.x;
  const int rg  = w >> 5;          // 0..3 -> rows rg*6..rg*6+5
  const int jg  = w & 31;          // 0..31
  const int j0  = jg * 16;         // 512-col matrices slice
  const int c0m = jg * 32;         // mlp1 1024-col slice
  const int bB  = w >> 4;          // batch owner for B1/B2 (16 WGs per batch)
  const int n0  = (w & 15) * 16;   // B1 n-slice
  const int j0b = (w & 15) * 32;   // B2 j-slice
  const int tid = threadIdx.x;
  const int wv  = tid >> 6, lane = tid & 63;
  const float scale = 0.04419417382415922f;  // 512^-0.5

  __shared__ float lnm[6], lnr[6];
  __shared__ float ghl[6][48];      // gh slice (3 gates x 16 j), WG-local
  __shared__ float gg[6][16][3];    // gi gates
  __shared__ float izl[3];          // 1/(Z+eps) for own batch
  __shared__ float pp[4][3][32];    // U partials over n-chunks

  for (int t = 0; t < CT; ++t) {
    for (int it = 0; it < NITER; ++it) {
      // ======== A: LN stats; gh (LDS-local); q slice (global) ========
      {
        int r = rg * 6 + wv;
        const float* srow = slots + r * CH;
        float s = 0.f;
#pragma unroll
        for (int i = 0; i < 8; ++i) s += srow[lane + 64 * i];
        for (int o = 32; o; o >>= 1) s += __shfl_xor(s, o);
        float mean = s * (1.f / CH);
        float s2 = 0.f;
#pragma unroll
        for (int i = 0; i < 8; ++i) { float d = srow[lane + 64 * i] - mean; s2 += d * d; }
        for (int o = 32; o; o >>= 1) s2 += __shfl_xor(s2, o);
        if (lane == 0) { lnm[wv] = mean; lnr[wv] = rsqrtf(s2 * (1.f / CH) + 1e-5f); }
      }
      __syncthreads();
      if (tid < 288) {  // gh: 6 rows x (3 gates x 16 j)
        int rl = tid / 48, ci = tid % 48;
        int gate = ci >> 4, jl = ci & 15;
        int col = gate * 512 + j0 + jl;
        const float* srow = slots + (rg * 6 + rl) * CH;
        const float* wc = whhT + col;
        float a0 = 0.f, a1 = 0.f, a2 = 0.f, a3 = 0.f;
        for (int k = 0; k < CH; k += 4) {
          a0 += srow[k]     * wc[(size_t)(k)     * CH3];
          a1 += srow[k + 1] * wc[(size_t)(k + 1) * CH3];
          a2 += srow[k + 2] * wc[(size_t)(k + 2) * CH3];
          a3 += srow[k + 3] * wc[(size_t)(k + 3) * CH3];
        }
        ghl[rl][ci] = a0 + a1 + a2 + a3 + b_hh[col];
      } else {          // q: 6 rows x 16 cols
        int t2 = tid - 288;
        int rl = t2 >> 4, cl = t2 & 15;
        int c = j0 + cl;
        const float* srow = slots + (rg * 6 + rl) * CH;
        float mean = lnm[rl], rstd = lnr[rl];
        const float* wc = wqT + c;
        float a0 = 0.f, a1 = 0.f, a2 = 0.f, a3 = 0.f;
        for (int k = 0; k < CH; k += 4) {
          float x0 = (srow[k]     - mean) * rstd * g_ls[k]     + b_ls[k];
          float x1 = (srow[k + 1] - mean) * rstd * g_ls[k + 1] + b_ls[k + 1];
          float x2 = (srow[k + 2] - mean) * rstd * g_ls[k + 2] + b_ls[k + 2];
          float x3 = (srow[k + 3] - mean) * rstd * g_ls[k + 3] + b_ls[k + 3];
          a0 += x0 * wc[(size_t)(k)     * CH];
          a1 += x1 * wc[(size_t)(k + 1) * CH];
          a2 += x2 * wc[(size_t)(k + 2) * CH];
          a3 += x3 * wc[(size_t)(k + 3) * CH];
        }
        qb[(rg * 6 + rl) * CH + c] = a0 + a1 + a2 + a3;
      }
      gbar(bar, nwg);
      // ======== B1: logits -> softmax over s -> attn (wave per (b,n)) ========
      {
        const float* q0 = qb + (bB * 3 + 0) * CH;
        const float* q1 = q0 + CH;
        const float* q2 = q1 + CH;
        for (int p = wv; p < 16; p += 6) {
          int n = n0 + p;
          const float* krow = kbuf + ((size_t)((bB * CT + t) * CN + n)) * CH;
          float p0 = 0.f, p1 = 0.f, p2 = 0.f;
#pragma unroll
          for (int i = 0; i < 8; ++i) {
            int k = lane + 64 * i;
            float kk = krow[k];
            p0 += q0[k] * kk; p1 += q1[k] * kk; p2 += q2[k] * kk;
          }
          for (int o = 32; o; o >>= 1) {
            p0 += __shfl_xor(p0, o); p1 += __shfl_xor(p1, o); p2 += __shfl_xor(p2, o);
          }
          p0 *= scale; p1 *= scale; p2 *= scale;
          float mx = fmaxf(p0, fmaxf(p1, p2));
          float e0 = expf(p0 - mx), e1 = expf(p1 - mx), e2 = expf(p2 - mx);
          float inv = 1.f / (e0 + e1 + e2);
          if (lane < 3) {
            float a = (lane == 0 ? e0 : (lane == 1 ? e1 : e2)) * inv;
            attnb[(bB * 3 + lane) * CN + n] = a;
            if (it == NITER - 1)
              att[((size_t)(bB * CT + t) * CS + lane) * CN + n] = a;
          }
        }
      }
      gbar(bar, nwg);
      // ======== B2: U = (attn/Z) @ v, slice (b, 32 j) ========
      if (tid < 192) {  // Z for own batch (redundant across its 16 WGs)
        int s = tid >> 6;
        const float* arow = attnb + (bB * 3 + s) * CN;
        float z = arow[lane] + arow[lane + 64] + arow[lane + 128] + arow[lane + 192];
        for (int o = 32; o; o >>= 1) z += __shfl_xor(z, o);
        if (lane == 0) izl[s] = 1.f / (z + 1e-8f);
      }
      {
        int t96 = tid % 96;
        int s = t96 >> 5, jl = t96 & 31, nch = tid / 96;
        const float* arow = attnb + (bB * 3 + s) * CN;
        const float* vcol = vbuf + ((size_t)((bB * CT + t) * CN)) * CH + j0b + jl;
        float acc = 0.f;
        int nstart = nch * 64;
        for (int n = nstart; n < nstart + 64; ++n)
          acc += arow[n] * vcol[(size_t)n * CH];
        pp[nch][s][jl] = acc;
      }
      __syncthreads();
      if (tid < 96) {
        int s = tid >> 5, jl = tid & 31;
        float u = (pp[0][s][jl] + pp[1][s][jl] + pp[2][s][jl] + pp[3][s][jl]) * izl[s];
        Ub[(bB * 3 + s) * CH + j0b + jl] = u;
      }
      gbar(bar, nwg);
      // ======== C: GRU gates (gi) + combine -> h slice ========
      if (tid < 288) {
        int o = tid % 96, gate = tid / 96;
        int rl = o >> 4, jl = o & 15;
        int col = gate * 512 + j0 + jl;
        const float* urow = Ub + (rg * 6 + rl) * CH;
        const float* wc = wihT + col;
        float a0 = 0.f, a1 = 0.f, a2 = 0.f, a3 = 0.f;
        for (int k = 0; k < CH; k += 4) {
          a0 += urow[k]     * wc[(size_t)(k)     * CH3];
          a1 += urow[k + 1] * wc[(size_t)(k + 1) * CH3];
          a2 += urow[k + 2] * wc[(size_t)(k + 2) * CH3];
          a3 += urow[k + 3] * wc[(size_t)(k + 3) * CH3];
        }
        gg[rl][jl][gate] = a0 + a1 + a2 + a3 + b_ih[col];
      }
      __syncthreads();
      if (tid < 96) {
        int rl = tid >> 4, jl = tid & 15;
        int r = rg * 6 + rl, j = j0 + jl;
        float ir = gg[rl][jl][0], iz = gg[rl][jl][1], inn = gg[rl][jl][2];
        float hr = ghl[rl][jl], hz = ghl[rl][16 + jl], hn = ghl[rl][32 + jl];
        float rr = 1.f / (1.f + expf(-(ir + hr)));
        float zz = 1.f / (1.f + expf(-(iz + hz)));
        float nn = tanhf(inn + rr * hn);
        hb[r * CH + j] = (1.f - zz) * nn + zz * slots[r * CH + j];
      }
      gbar(bar, nwg);
      // ======== D: y = gelu(LN(h) @ w_mlp1.T + b) slice (6 r x 32 c) ========
      {
        int r = rg * 6 + wv;
        const float* hrow = hb + r * CH;
        float s = 0.f;
#pragma unroll
        for (int i = 0; i < 8; ++i) s += hrow[lane + 64 * i];
        for (int o = 32; o; o >>= 1) s += __shfl_xor(s, o);
        float mean = s * (1.f / CH);
        float s2 = 0.f;
#pragma unroll
        for (int i = 0; i < 8; ++i) { float d = hrow[lane + 64 * i] - mean; s2 += d * d; }
        for (int o = 32; o; o >>= 1) s2 += __shfl_xor(s2, o);
        if (lane == 0) { lnm[wv] = mean; lnr[wv] = rsqrtf(s2 * (1.f / CH) + 1e-5f); }
      }
      __syncthreads();
      if (tid < 192) {
        int rl = tid >> 5, cl = tid & 31;
        int c = c0m + cl;
        const float* hrow = hb + (rg * 6 + rl) * CH;
        float mean = lnm[rl], rstd = lnr[rl];
        const float* wc = wm1T + c;
        float a0 = 0.f, a1 = 0.f, a2 = 0.f, a3 = 0.f;
        for (int k = 0; k < CH; k += 4) {
          float x0 = (hrow[k]     - mean) * rstd * g_lm[k]     + b_lm[k];
          float x1 = (hrow[k + 1] - mean) * rstd * g_lm[k + 1] + b_lm[k + 1];
          float x2 = (hrow[k + 2] - mean) * rstd * g_lm[k + 2] + b_lm[k + 2];
          float x3 = (hrow[k + 3] - mean) * rstd * g_lm[k + 3] + b_lm[k + 3];
          a0 += x0 * wc[(size_t)(k)     * CH2];
          a1 += x1 * wc[(size_t)(k + 1) * CH2];
          a2 += x2 * wc[(size_t)(k + 2) * CH2];
          a3 += x3 * wc[(size_t)(k + 3) * CH2];
        }
        float acc = a0 + a1 + a2 + a3 + b_m1[c];
        float g = 0.5f * acc * (1.f + erff(acc * 0.70710678118654752f));
        yb[(rg * 6 + rl) * CH2 + c] = g;
      }
      gbar(bar, nwg);
      // ======== E: slots' = h + y @ w_mlp2.T + b (6 r x 16 j) ========
      if (tid < 96) {
        int rl = tid >> 4, jl = tid & 15;
        int r = rg * 6 + rl, j = j0 + jl;
        const float* yrow = yb + r * CH2;
        const float* wc = wm2T + j;
        float a0 = 0.f, a1 = 0.f, a2 = 0.f, a3 = 0.f;
        for (int k = 0; k < CH2; k += 4) {
          a0 += yrow[k]     * wc[(size_t)(k)     * CH];
          a1 += yrow[k + 1] * wc[(size_t)(k + 1) * CH];
          a2 += yrow[k + 2] * wc[(size_t)(k + 2) * CH];
          a3 += yrow[k + 3] * wc[(size_t)(k + 3) * CH];
        }
        float sn = hb[r * CH + j] + a0 + a1 + a2 + a3 + b_m2[j];
        slots[r * CH + j] = sn;
        if (it == NITER - 1) {
          int b = r / 3, s5 = r % 3;
          spf[((size_t)(b * CT + t) * CS + s5) * CH + j] = sn;
        }
      }
      gbar(bar, nwg);
    }
  }
}

// ================= temporal attention: qkv projection =================
__global__ __launch_bounds__(256) void k_tproj(const float* __restrict__ spf,
                                               const float* __restrict__ ws_c,
                                               const float* __restrict__ b_tq,
                                               const float* __restrict__ b_tk,
                                               const float* __restrict__ b_tv,
                                               float* __restrict__ tqkv) {
  __shared__ float xr[CH];
  int row = blockIdx.x;  // bs*16 + t
  int bs = row >> 4, t = row & 15;
  int b = bs / 3, s = bs % 3;
  const float* x = spf + ((size_t)(b * CT + t) * CS + s) * CH;
  for (int i = threadIdx.x; i < CH; i += 256) xr[i] = x[i];
  __syncthreads();
  for (int p = 0; p < 6; ++p) {
    int j = p * 256 + threadIdx.x;
    const float* wT; const float* bb; int jj;
    if (j < 512)      { wT = ws_c + OFS_WTQT; bb = b_tq; jj = j; }
    else if (j < 1024){ wT = ws_c + OFS_WTKT; bb = b_tk; jj = j - 512; }
    else              { wT = ws_c + OFS_WTVT; bb = b_tv; jj = j - 1024; }
    float acc = bb[jj];
    for (int h = 0; h < CH; ++h) acc += xr[h] * wT[h * CH + jj];
    tqkv[(size_t)row * CH3 + j] = acc;
  }
}

// ================= temporal attention: per (track, head) =================
__global__ __launch_bounds__(64) void k_tattn(const float* __restrict__ tqkv,
                                              float* __restrict__ ob) {
  __shared__ float qs[16][68], ks[16][68], vs[16][68], sc[16][20];
  int bs = blockIdx.x >> 3, hh = blockIdx.x & 7;
  int lane = threadIdx.x;
  for (int i = 0; i < 16; ++i) {
    const float* base = tqkv + (size_t)(bs * 16 + i) * CH3 + hh * 64;
    qs[i][lane] = base[lane];
    ks[i][lane] = base[512 + lane];
    vs[i][lane] = base[1024 + lane];
  }
  __syncthreads();
  for (int u = 0; u < 4; ++u) {
    int ee = u * 64 + lane;
    int i = ee >> 4, j = ee & 15;
    float acc = 0.f;
    for (int d = 0; d < 64; ++d) acc += qs[i][d] * ks[j][d];
    sc[i][j] = acc * 0.125f;  // 1/sqrt(64)
  }
  __syncthreads();
  if (lane < 16) {
    float mx = -1e30f;
    for (int j = 0; j < 16; ++j) mx = fmaxf(mx, sc[lane][j]);
    float sum = 0.f;
    for (int j = 0; j < 16; ++j) { float ev = expf(sc[lane][j] - mx); sc[lane][j] = ev; sum += ev; }
    float inv = 1.f / sum;
    for (int j = 0; j < 16; ++j) sc[lane][j] *= inv;
  }
  __syncthreads();
  for (int i = 0; i < 16; ++i) {
    float acc = 0.f;
    for (int j = 0; j < 16; ++j) acc += sc[i][j] * vs[j][lane];
    ob[(size_t)(bs * 16 + i) * CH + hh * 64 + lane] = acc;
  }
}

// ================= temporal out-proj + residual + LN + mean =================
__global__ __launch_bounds__(256) void k_tout(const float* __restrict__ ob,
                                              const float* __restrict__ spf,
                                              const float* __restrict__ ws_c,
                                              const float* __restrict__ b_to,
                                              const float* __restrict__ g_lt,
                                              const float* __restrict__ b_lt,
                                              float* __restrict__ agg) {
  __shared__ float orow[CH], rrow[CH], red[8];
  int row = blockIdx.x;
  int bs = row >> 4, t = row & 15;
  int b = bs / 3, s = bs % 3;
  const float* x = spf + ((size_t)(b * CT + t) * CS + s) * CH;
  const float* o = ob + (size_t)row * CH;
  for (int i = threadIdx.x; i < CH; i += 256) orow[i] = o[i];
  __syncthreads();
  const float* wto = ws_c + OFS_WTOT;
  for (int p = 0; p < 2; ++p) {
    int j = p * 256 + threadIdx.x;
    float acc = b_to[j];
    for (int c = 0; c < CH; ++c) acc += orow[c] * wto[c * CH + j];
    rrow[j] = acc + x[j];
  }
  __syncthreads();
  float part = rrow[threadIdx.x] + rrow[threadIdx.x + 256];
  for (int o2 = 32; o2; o2 >>= 1) part += __shfl_xor(part, o2);
  if ((threadIdx.x & 63) == 0) red[threadIdx.x >> 6] = part;
  __syncthreads();
  float mean = (red[0] + red[1] + red[2] + red[3]) * (1.f / CH);
  float d0 = rrow[threadIdx.x] - mean, d1 = rrow[threadIdx.x + 256] - mean;
  float p2 = d0 * d0 + d1 * d1;
  for (int o2 = 32; o2; o2 >>= 1) p2 += __shfl_xor(p2, o2);
  __syncthreads();
  if ((threadIdx.x & 63) == 0) red[(threadIdx.x >> 6) + 4] = p2;
  __syncthreads();
  float rstd = rsqrtf((red[4] + red[5] + red[6] + red[7]) * (1.f / CH) + 1e-5f);
  for (int p = 0; p < 2; ++p) {
    int j = p * 256 + threadIdx.x;
    float xt = (rrow[j] - mean) * rstd * g_lt[j] + b_lt[j];
    atomicAdd(&agg[(size_t)bs * CH + j], xt * (1.f / CT));
  }
}

// ================= launch =================
extern "C" void kernel_launch(void* const* d_in, const int* in_sizes, int n_in,
                              void* d_out, int out_size, void* d_ws, size_t ws_size,
                              hipStream_t stream) {
  (void)in_sizes; (void)n_in; (void)out_size; (void)ws_size;
  const float* visual = (const float*)d_in[0];
  const float* noise  = (const float*)d_in[1];
  const float* mu     = (const float*)d_in[2];
  const float* sigma  = (const float*)d_in[3];
  const float* w_in   = (const float*)d_in[4];
  const float* b_in   = (const float*)d_in[5];
  const float* g_lin  = (const float*)d_in[6];
  const float* b_lin  = (const float*)d_in[7];
  const float* w_m1p  = (const float*)d_in[8];
  const float* b_m1p  = (const float*)d_in[9];
  const float* w_m2p  = (const float*)d_in[10];
  const float* b_m2p  = (const float*)d_in[11];
  const float* w_q    = (const float*)d_in[12];
  const float* w_k    = (const float*)d_in[13];
  const float* w_v    = (const float*)d_in[14];
  const float* w_ih   = (const float*)d_in[15];
  const float* w_hh   = (const float*)d_in[16];
  const float* b_ih   = (const float*)d_in[17];
  const float* b_hh   = (const float*)d_in[18];
  const float* g_ls   = (const float*)d_in[19];
  const float* b_ls   = (const float*)d_in[20];
  const float* g_lm   = (const float*)d_in[21];
  const float* b_lm   = (const float*)d_in[22];
  const float* w_mlp1 = (const float*)d_in[23];
  const float* b_mlp1 = (const float*)d_in[24];
  const float* w_mlp2 = (const float*)d_in[25];
  const float* b_mlp2 = (const float*)d_in[26];
  const float* w_tq   = (const float*)d_in[27];
  const float* b_tq   = (const float*)d_in[28];
  const float* w_tk   = (const float*)d_in[29];
  const float* b_tk   = (const float*)d_in[30];
  const float* w_tv   = (const float*)d_in[31];
  const float* b_tv   = (const float*)d_in[32];
  const float* w_to   = (const float*)d_in[33];
  const float* b_to   = (const float*)d_in[34];
  const float* g_lt   = (const float*)d_in[35];
  const float* b_lt   = (const float*)d_in[36];

  float* ws  = (float*)d_ws;
  float* out = (float*)d_out;
  float* spf = out + 12288;
  float* att = out + 12288 + 196608;

  hipLaunchKernelGGL(k_init, dim3(48), dim3(256), 0, stream, noise, mu, sigma, ws, out);
  hipLaunchKernelGGL(k_transpose, dim3(32, 48, 9), dim3(256), 0, stream,
                     w_q, w_hh, w_ih, w_mlp1, w_mlp2, w_to, w_tq, w_tk, w_tv, ws);
  // Stage 1
  hipLaunchKernelGGL(k_p1, dim3(4, 256), dim3(256), 0, stream,
                     visual, w_in, b_in, ws + OFS_P1);
  hipLaunchKernelGGL(k_rowstats, dim3(CM / 4), dim3(256), 0, stream,
                     ws + OFS_P1, ws + OFS_ST);
  hipLaunchKernelGGL(k_m1, dim3(4, 256), dim3(256), 0, stream,
                     visual, w_m1p, b_m1p, ws + OFS_M1);
  hipLaunchKernelGGL(k_feats, dim3(4, 256), dim3(256), 0, stream,
                     ws + OFS_M1, w_m2p, b_m2p, ws + OFS_ST, g_lin, b_lin, ws + OFS_P1);
  hipLaunchKernelGGL(k_kv, dim3(8, 256), dim3(256), 0, stream,
                     ws + OFS_P1, w_k, w_v, ws + OFS_M1, ws + OFS_V);
  // Stage 2: persistent scan (128 co-resident WGs, output-sliced, custom device barrier)
  hipLaunchKernelGGL(k_scan, dim3(128), dim3(384), 0, stream,
                     ws, b_ih, b_hh, g_ls, b_ls, g_lm, b_lm, b_mlp1, b_mlp2,
                     spf, att, 128);
  // Stage 3: temporal attention
  hipLaunchKernelGGL(k_tproj, dim3(384), dim3(256), 0, stream,
                     spf, ws, b_tq, b_tk, b_tv, ws + OFS_TQKV);
  hipLaunchKernelGGL(k_tattn, dim3(192), dim3(64), 0, stream,
                     ws + OFS_TQKV, ws + OFS_TO);
  hipLaunchKernelGGL(k_tout, dim3(384), dim3(256), 0, stream,
                     ws + OFS_TO, spf, ws, b_to, g_lt, b_lt, out);
}